// Round 7
// baseline (188.931 us; speedup 1.0000x reference)
//
#include <hip/hip_runtime.h>
#include <math.h>

typedef __bf16 bf16x8 __attribute__((ext_vector_type(8)));
typedef float f32x4 __attribute__((ext_vector_type(4)));
typedef unsigned short u16;
typedef u16 u16x8 __attribute__((ext_vector_type(8)));

// clip(round(x*inv), -128, 127) -- rintf = round-half-even, matches jnp.round
__device__ __forceinline__ float quantq_inv(float x, float inv) {
    return fminf(fmaxf(rintf(x * inv), -128.f), 127.f);
}

__device__ __forceinline__ u16 sign_bf16(float w) {
    return (w > 0.f) ? (u16)0x3F80 : ((w < 0.f) ? (u16)0xBF80 : (u16)0);
}

// ---------------- prep 1: per-slice |w| partial sums (deterministic) --------
__global__ void alpha_part(const float* __restrict__ w1,
                           const float* __restrict__ w2,
                           const float* __restrict__ w3,
                           float* __restrict__ partial) {
    __shared__ float red[256];
    const int bid = blockIdx.x;
    const int m = bid >> 5, i = bid & 31;
    const float* w = (m == 0) ? w1 : ((m == 1) ? w2 : w3);
    const int n = (m == 0) ? 100352 : ((m == 1) ? 16384 : 1280);
    const int chunk = n >> 5;  // all divisible by 32
    const float* p = w + i * chunk;
    float s = 0.f;
    for (int t = threadIdx.x; t < chunk; t += 256) s += fabsf(p[t]);
    red[threadIdx.x] = s;
    __syncthreads();
    for (int off = 128; off > 0; off >>= 1) {
        if ((int)threadIdx.x < off) red[threadIdx.x] += red[threadIdx.x + off];
        __syncthreads();
    }
    if (threadIdx.x == 0) partial[bid] = red[0];
}

// ---------------- prep 2: pack sign(w) frag-ready + finalize alphas ---------
// dest layout per kstep(K=32): [ntile][lane][8] where for B-operand of
// mfma_f32_16x16x32_bf16: lane = (kk/8)*16 + (col%16), j = kk%8
__global__ void pack_kernel(const float* __restrict__ w1,
                            const float* __restrict__ w2,
                            const float* __restrict__ w3,
                            u16* __restrict__ Wb1,
                            const float* __restrict__ partial,
                            float* __restrict__ alphas) {
    if (blockIdx.x == 0 && threadIdx.x < 3) {
        const int t = threadIdx.x;
        float s = 0.f;
        for (int i = 0; i < 32; ++i) s += partial[t * 32 + i];
        const int n = (t == 0) ? 100352 : ((t == 1) ? 16384 : 1280);
        alphas[t] = s / (float)n;
    }
    u16* Wb2 = Wb1 + 102400;
    u16* Wb3 = Wb2 + 16384;
    int idx = blockIdx.x * 256 + threadIdx.x;
    if (idx < 102400) {
        int k = idx >> 7, n = idx & 127;
        u16 v = (k < 784) ? sign_bf16(w1[k * 128 + n]) : (u16)0;
        int dest = ((((k >> 5) * 8 + (n >> 4)) * 64) + ((((k & 31) >> 3) << 4) | (n & 15))) * 8 + (k & 7);
        Wb1[dest] = v;
    } else if (idx < 102400 + 16384) {
        int i = idx - 102400;
        int k = i >> 7, n = i & 127;
        u16 v = sign_bf16(w2[k * 128 + n]);
        int dest = ((((k >> 5) * 8 + (n >> 4)) * 64) + ((((k & 31) >> 3) << 4) | (n & 15))) * 8 + (k & 7);
        Wb2[dest] = v;
    } else if (idx < 102400 + 16384 + 2048) {
        int i = idx - 102400 - 16384;
        int k = i >> 4, n = i & 15;
        u16 v = (n < 10) ? sign_bf16(w3[k * 10 + n]) : (u16)0;
        int dest = (((k >> 5) * 64) + ((((k & 31) >> 3) << 4) | n)) * 8 + (k & 7);
        Wb3[dest] = v;
    }
}

// ---------------- fused forward: 64 rows/block, 4 waves, ZERO barriers ------
// R3 structure (best: 114.7us). This round's single change: h1/h2/out0/h3
// stores are REGULAR (L2 write-back, line merging) instead of nontemporal --
// NT 4B/64B-granule stores defeat write-combining -> partial-line HBM writes.
// h0 keeps NT: its lane-quad pattern covers full 128B lines.
__global__ __launch_bounds__(256, 4) void fused_kernel(
    const float* __restrict__ input,
    const float* __restrict__ bias1, const float* __restrict__ bias2,
    const float* __restrict__ bias3,
    const float* __restrict__ ps_in, const float* __restrict__ ps1i,
    const float* __restrict__ ps1o, const float* __restrict__ ps2i,
    const float* __restrict__ ps2o, const float* __restrict__ ps3i,
    const float* __restrict__ ps3o,
    const float* __restrict__ alphas, const u16* __restrict__ Wb1,
    float* __restrict__ out0, float* __restrict__ h0, float* __restrict__ h1,
    float* __restrict__ h2, float* __restrict__ h3)
{
    const u16* Wb2 = Wb1 + 102400;
    const u16* Wb3 = Wb2 + 16384;

    // wave-local inter-layer exchange only (no block barriers anywhere)
    __shared__ u16 A2[8192];  // [ks(4)][wave(4)][lane(64)][8] : 64 rows x 128 k

    const int tid = threadIdx.x;
    const int wave = tid >> 6, lane = tid & 63;
    const int row0 = blockIdx.x * 64;

    const float s_in = *ps_in, s1i = *ps1i, s1o = *ps1o;
    const float s2i = *ps2i, s2o = *ps2o, s3i = *ps3i, s3o = *ps3o;
    const float inv_sin = 1.f / s_in, inv_s1i = 1.f / s1i, inv_s1o = 1.f / s1o;
    const float inv_s2i = 1.f / s2i, inv_s2o = 1.f / s2o;
    const float inv_s3i = 1.f / s3i, inv_s3o = 1.f / s3o;
    const float alpha1 = alphas[0], alpha2 = alphas[1], alpha3 = alphas[2];

    // A-frag ownership: row = lane&15 (within wave's 16-row tile), kgroup = lane>>4
    const int rA = lane & 15;
    const int gA = lane >> 4;
    const size_t arow = (size_t)(row0 + wave * 16 + rA) * 784;
    const float* __restrict__ inA = input + arow + gA * 8;
    float* __restrict__ h0A = h0 + arow + gA * 8;
    const u16* bw1 = Wb1 + (size_t)lane * 8;

    f32x4 acc1[8];
#pragma unroll
    for (int n = 0; n < 8; ++n) acc1[n] = f32x4{0.f, 0.f, 0.f, 0.f};

    // quant + h0-store + pack + 8 MFMAs for one kstep's 8 owned elements
    auto consume = [&](int ksq, f32x4 va, f32x4 vb, bool dostore) {
        float q[8];
#pragma unroll
        for (int j = 0; j < 4; ++j) {
            q[j]     = quantq_inv(va[j], inv_sin);
            q[4 + j] = quantq_inv(vb[j], inv_sin);
        }
        if (dostore) {
            f32x4 ha = {q[0] * s_in, q[1] * s_in, q[2] * s_in, q[3] * s_in};
            f32x4 hb = {q[4] * s_in, q[5] * s_in, q[6] * s_in, q[7] * s_in};
            float* hp = h0A + ksq * 32;
            __builtin_nontemporal_store(ha, reinterpret_cast<f32x4*>(hp));
            __builtin_nontemporal_store(hb, reinterpret_cast<f32x4*>(hp + 4));
        }
        u16x8 qb;
#pragma unroll
        for (int j = 0; j < 8; ++j) qb[j] = (u16)(__float_as_uint(q[j]) >> 16);
        union { u16x8 u; bf16x8 b; } cvt;
        cvt.u = qb;
        const bf16x8 a = cvt.b;
        const u16* bp = bw1 + (size_t)ksq * 4096;
#pragma unroll
        for (int n = 0; n < 8; ++n) {
            const bf16x8 b = *reinterpret_cast<const bf16x8*>(bp + n * 512);
            acc1[n] = __builtin_amdgcn_mfma_f32_16x16x32_bf16(a, b, acc1[n], 0, 0, 0);
        }
    };

    // ---- layer 1: K=784 padded to 800 (25 ksteps), 4-deep static ring ------
    f32x4 s0a, s0b, s1a, s1b, s2a, s2b, s3a, s3b;
    s0a = *reinterpret_cast<const f32x4*>(inA + 0 * 32);
    s0b = *reinterpret_cast<const f32x4*>(inA + 0 * 32 + 4);
    s1a = *reinterpret_cast<const f32x4*>(inA + 1 * 32);
    s1b = *reinterpret_cast<const f32x4*>(inA + 1 * 32 + 4);
    s2a = *reinterpret_cast<const f32x4*>(inA + 2 * 32);
    s2b = *reinterpret_cast<const f32x4*>(inA + 2 * 32 + 4);
    s3a = *reinterpret_cast<const f32x4*>(inA + 3 * 32);
    s3b = *reinterpret_cast<const f32x4*>(inA + 3 * 32 + 4);

#define L1_STEP(K, SA, SB)                                                    \
    {                                                                         \
        f32x4 na, nb;                                                         \
        const int t_ = (K) + 4;                                               \
        if (t_ < 24) {                                                        \
            na = *reinterpret_cast<const f32x4*>(inA + t_ * 32);              \
            nb = *reinterpret_cast<const f32x4*>(inA + t_ * 32 + 4);          \
        } else if (t_ == 24) {                                                \
            if (gA < 2) {                                                     \
                na = *reinterpret_cast<const f32x4*>(inA + 768);              \
                nb = *reinterpret_cast<const f32x4*>(inA + 768 + 4);          \
            } else {                                                          \
                na = f32x4{0.f, 0.f, 0.f, 0.f};                               \
                nb = f32x4{0.f, 0.f, 0.f, 0.f};                               \
            }                                                                 \
        } else {                                                              \
            na = SA; nb = SB;                                                 \
        }                                                                     \
        consume((K), SA, SB, true);                                           \
        SA = na; SB = nb;                                                     \
    }

#pragma unroll
    for (int base = 0; base < 24; base += 4) {
        L1_STEP(base + 0, s0a, s0b);
        L1_STEP(base + 1, s1a, s1b);
        L1_STEP(base + 2, s2a, s2b);
        L1_STEP(base + 3, s3a, s3b);
    }
#undef L1_STEP

    // tail kstep ksq=24 (cols 768..800; valid only for gA<2, slots hold zeros
    // for gA>=2 so quant yields exact 0 -> qb=0)
    {
        float q[8];
#pragma unroll
        for (int j = 0; j < 4; ++j) {
            q[j]     = quantq_inv(s0a[j], inv_sin);
            q[4 + j] = quantq_inv(s0b[j], inv_sin);
        }
        if (gA < 2) {
            f32x4 ha = {q[0] * s_in, q[1] * s_in, q[2] * s_in, q[3] * s_in};
            f32x4 hb = {q[4] * s_in, q[5] * s_in, q[6] * s_in, q[7] * s_in};
            float* hp = h0A + 24 * 32;
            __builtin_nontemporal_store(ha, reinterpret_cast<f32x4*>(hp));
            __builtin_nontemporal_store(hb, reinterpret_cast<f32x4*>(hp + 4));
        }
        u16x8 qb;
#pragma unroll
        for (int j = 0; j < 8; ++j) qb[j] = (u16)(__float_as_uint(q[j]) >> 16);
        union { u16x8 u; bf16x8 b; } cvt;
        cvt.u = qb;
        const bf16x8 a = cvt.b;
        const u16* bp = bw1 + (size_t)24 * 4096;
#pragma unroll
        for (int n = 0; n < 8; ++n) {
            const bf16x8 b = *reinterpret_cast<const bf16x8*>(bp + n * 512);
            acc1[n] = __builtin_amdgcn_mfma_f32_16x16x32_bf16(a, b, acc1[n], 0, 0, 0);
        }
    }

    // ---- layer 1 epilogue: requantize, write h1, restage A2 (wave-local) ----
    const int cl = lane & 15;
    const int rh = lane >> 4;
    {
        const float a1s = alpha1 * s_in;
#pragma unroll
        for (int n = 0; n < 8; ++n) {
            const int col = n * 16 + cl;
            const float bias = bias1[col];
            const int ks = n >> 1;
            const int gk = ((n & 1) * 2) + (cl >> 3);
            const int jd = cl & 7;
#pragma unroll
            for (int j = 0; j < 4; ++j) {
                const int rl = rh * 4 + j;
                float x = a1s * acc1[n][j] + bias;
                x = quantq_inv(x, inv_s1i) * s1i;
                x = fmaxf(x, 0.f);
                const float qv = quantq_inv(x, inv_s1o);
                h1[(size_t)(row0 + wave * 16 + rl) * 128 + col] = qv * s1o;
                A2[(((ks * 4 + wave) * 64) + (gk * 16 + rl)) * 8 + jd] =
                    (u16)(__float_as_uint(qv) >> 16);
            }
        }
    }

    // ---- layer 2: K=128 (4 ksteps), B-frags straight from global (L1) ----
    f32x4 acc2[8];
#pragma unroll
    for (int n = 0; n < 8; ++n) acc2[n] = f32x4{0.f, 0.f, 0.f, 0.f};
#pragma unroll
    for (int ks = 0; ks < 4; ++ks) {
        const bf16x8 a = *reinterpret_cast<const bf16x8*>(&A2[((ks * 4 + wave) * 64 + lane) * 8]);
#pragma unroll
        for (int n = 0; n < 8; ++n) {
            const bf16x8 b = *reinterpret_cast<const bf16x8*>(Wb2 + ((size_t)(ks * 8 + n) * 64 + lane) * 8);
            acc2[n] = __builtin_amdgcn_mfma_f32_16x16x32_bf16(a, b, acc2[n], 0, 0, 0);
        }
    }

    // ---- layer 2 epilogue ----
    {
        const float a2s = alpha2 * s1o;
#pragma unroll
        for (int n = 0; n < 8; ++n) {
            const int col = n * 16 + cl;
            const float bias = bias2[col];
            const int ks = n >> 1;
            const int gk = ((n & 1) * 2) + (cl >> 3);
            const int jd = cl & 7;
#pragma unroll
            for (int j = 0; j < 4; ++j) {
                const int rl = rh * 4 + j;
                float x = a2s * acc2[n][j] + bias;
                x = quantq_inv(x, inv_s2i) * s2i;
                x = fmaxf(x, 0.f);
                const float qv = quantq_inv(x, inv_s2o);
                h2[(size_t)(row0 + wave * 16 + rl) * 128 + col] = qv * s2o;
                A2[(((ks * 4 + wave) * 64) + (gk * 16 + rl)) * 8 + jd] =
                    (u16)(__float_as_uint(qv) >> 16);
            }
        }
    }

    // ---- layer 3: K=128, single ntile (N=10 padded to 16) ----
    f32x4 acc3 = f32x4{0.f, 0.f, 0.f, 0.f};
#pragma unroll
    for (int ks = 0; ks < 4; ++ks) {
        const bf16x8 a = *reinterpret_cast<const bf16x8*>(&A2[((ks * 4 + wave) * 64 + lane) * 8]);
        const bf16x8 b = *reinterpret_cast<const bf16x8*>(Wb3 + ((size_t)ks * 64 + lane) * 8);
        acc3 = __builtin_amdgcn_mfma_f32_16x16x32_bf16(a, b, acc3, 0, 0, 0);
    }

    // ---- layer 3 epilogue: sigmoid + quant, write h3 and out0 ----
    if (cl < 10) {
        const float a3s = alpha3 * s2o;
        const float bias = bias3[cl];
#pragma unroll
        for (int j = 0; j < 4; ++j) {
            const int rgl = row0 + wave * 16 + rh * 4 + j;
            float x = a3s * acc3[j] + bias;
            x = quantq_inv(x, inv_s3i) * s3i;
            const float sg = 1.f / (1.f + expf(-x));
            const float qv = quantq_inv(sg, inv_s3o) * s3o;
            out0[(size_t)rgl * 10 + cl] = qv;
            h3[(size_t)rgl * 10 + cl] = qv;
        }
    }
}

extern "C" void kernel_launch(void* const* d_in, const int* in_sizes, int n_in,
                              void* d_out, int out_size, void* d_ws, size_t ws_size,
                              hipStream_t stream) {
    const float* input = (const float*)d_in[0];
    const float* w1    = (const float*)d_in[1];
    const float* bias1 = (const float*)d_in[2];
    const float* w2    = (const float*)d_in[3];
    const float* bias2 = (const float*)d_in[4];
    const float* w3    = (const float*)d_in[5];
    const float* bias3 = (const float*)d_in[6];
    const float* s_in  = (const float*)d_in[7];
    const float* s1i   = (const float*)d_in[8];
    const float* s1o   = (const float*)d_in[9];
    const float* s2i   = (const float*)d_in[10];
    const float* s2o   = (const float*)d_in[11];
    const float* s3i   = (const float*)d_in[12];
    const float* s3o   = (const float*)d_in[13];

    float* out = (float*)d_out;
    // output order: (x_final, h0, h1, h2, h3)
    float* out0 = out;
    float* h0 = out + 655360;                   // 65536*10
    float* h1 = out + 52035584;                 // + 65536*784
    float* h2 = out + 60424192;                 // + 65536*128
    float* h3 = out + 68812800;                 // + 65536*128

    float* alphas  = (float*)d_ws;                        // 3 floats
    float* partial = (float*)((char*)d_ws + 16);          // 96 floats
    u16*   Wb1     = (u16*)((char*)d_ws + 512);           // 120832 u16

    alpha_part<<<96, 256, 0, stream>>>(w1, w2, w3, partial);
    pack_kernel<<<472, 256, 0, stream>>>(w1, w2, w3, Wb1, partial, alphas);
    fused_kernel<<<1024, 256, 0, stream>>>(input, bias1, bias2, bias3,
                                           s_in, s1i, s1o, s2i, s2o, s3i, s3o,
                                           alphas, Wb1,
                                           out0, h0, h1, h2, h3);
}

// Round 8
// 108.835 us; speedup vs baseline: 1.7359x; 1.7359x over previous
//
#include <hip/hip_runtime.h>
#include <math.h>

typedef __bf16 bf16x8 __attribute__((ext_vector_type(8)));
typedef float f32x4 __attribute__((ext_vector_type(4)));
typedef unsigned short u16;
typedef u16 u16x8 __attribute__((ext_vector_type(8)));
typedef u16 u16x4 __attribute__((ext_vector_type(4)));

// clip(round(x*inv), -128, 127) -- rintf = round-half-even, matches jnp.round
__device__ __forceinline__ float quantq_inv(float x, float inv) {
    return fminf(fmaxf(rintf(x * inv), -128.f), 127.f);
}

__device__ __forceinline__ u16 sign_bf16(float w) {
    return (w > 0.f) ? (u16)0x3F80 : ((w < 0.f) ? (u16)0xBF80 : (u16)0);
}

__device__ __forceinline__ float bfbits_to_f32(u16 b) {
    return __uint_as_float(((unsigned)b) << 16);
}

// ---------------- prep 1: per-slice |w| partial sums (deterministic) --------
__global__ void alpha_part(const float* __restrict__ w1,
                           const float* __restrict__ w2,
                           const float* __restrict__ w3,
                           float* __restrict__ partial) {
    __shared__ float red[256];
    const int bid = blockIdx.x;
    const int m = bid >> 5, i = bid & 31;
    const float* w = (m == 0) ? w1 : ((m == 1) ? w2 : w3);
    const int n = (m == 0) ? 100352 : ((m == 1) ? 16384 : 1280);
    const int chunk = n >> 5;  // all divisible by 32
    const float* p = w + i * chunk;
    float s = 0.f;
    for (int t = threadIdx.x; t < chunk; t += 256) s += fabsf(p[t]);
    red[threadIdx.x] = s;
    __syncthreads();
    for (int off = 128; off > 0; off >>= 1) {
        if ((int)threadIdx.x < off) red[threadIdx.x] += red[threadIdx.x + off];
        __syncthreads();
    }
    if (threadIdx.x == 0) partial[bid] = red[0];
}

// ---------------- prep 2: pack sign(w) frag-ready + finalize alphas ---------
// dest layout per kstep(K=32): [ntile][lane][8] where for B-operand of
// mfma_f32_16x16x32_bf16: lane = (kk/8)*16 + (col%16), j = kk%8
__global__ void pack_kernel(const float* __restrict__ w1,
                            const float* __restrict__ w2,
                            const float* __restrict__ w3,
                            u16* __restrict__ Wb1,
                            const float* __restrict__ partial,
                            float* __restrict__ alphas) {
    if (blockIdx.x == 0 && threadIdx.x < 3) {
        const int t = threadIdx.x;
        float s = 0.f;
        for (int i = 0; i < 32; ++i) s += partial[t * 32 + i];
        const int n = (t == 0) ? 100352 : ((t == 1) ? 16384 : 1280);
        alphas[t] = s / (float)n;
    }
    u16* Wb2 = Wb1 + 102400;
    u16* Wb3 = Wb2 + 16384;
    int idx = blockIdx.x * 256 + threadIdx.x;
    if (idx < 102400) {
        int k = idx >> 7, n = idx & 127;
        u16 v = (k < 784) ? sign_bf16(w1[k * 128 + n]) : (u16)0;
        int dest = ((((k >> 5) * 8 + (n >> 4)) * 64) + ((((k & 31) >> 3) << 4) | (n & 15))) * 8 + (k & 7);
        Wb1[dest] = v;
    } else if (idx < 102400 + 16384) {
        int i = idx - 102400;
        int k = i >> 7, n = i & 127;
        u16 v = sign_bf16(w2[k * 128 + n]);
        int dest = ((((k >> 5) * 8 + (n >> 4)) * 64) + ((((k & 31) >> 3) << 4) | (n & 15))) * 8 + (k & 7);
        Wb2[dest] = v;
    } else if (idx < 102400 + 16384 + 2048) {
        int i = idx - 102400 - 16384;
        int k = i >> 4, n = i & 15;
        u16 v = (n < 10) ? sign_bf16(w3[k * 10 + n]) : (u16)0;
        int dest = (((k >> 5) * 64) + ((((k & 31) >> 3) << 4) | n)) * 8 + (k & 7);
        Wb3[dest] = v;
    }
}

// ---------------- fused forward: 64 rows/block, 4 waves, ZERO barriers ------
// R3 structure (best: 114.7us), NT stores everywhere (R7 showed regular
// stores' ack latency backpressures vmcnt). This round: epilogue stores
// (h1/h2/out0/h3) are LDS-staged and written as FULL-LINE contiguous NT
// bursts (1KB/instr for h1/h2, 640B/wave for out0/h3) instead of scattered
// 4B stores. Hot loop untouched.
__global__ __launch_bounds__(256, 4) void fused_kernel(
    const float* __restrict__ input,
    const float* __restrict__ bias1, const float* __restrict__ bias2,
    const float* __restrict__ bias3,
    const float* __restrict__ ps_in, const float* __restrict__ ps1i,
    const float* __restrict__ ps1o, const float* __restrict__ ps2i,
    const float* __restrict__ ps2o, const float* __restrict__ ps3i,
    const float* __restrict__ ps3o,
    const float* __restrict__ alphas, const u16* __restrict__ Wb1,
    float* __restrict__ out0, float* __restrict__ h0, float* __restrict__ h1,
    float* __restrict__ h2, float* __restrict__ h3)
{
    const u16* Wb2 = Wb1 + 102400;
    const u16* Wb3 = Wb2 + 16384;

    // wave-local inter-layer exchange only (no block barriers anywhere)
    __shared__ u16 A2[8192];       // 16KB frag-layout activations
    __shared__ char Hraw[16384];   // 16KB: per-wave 4KB store-staging buffer

    const int tid = threadIdx.x;
    const int wave = tid >> 6, lane = tid & 63;
    const int row0 = blockIdx.x * 64;

    u16* Hb = reinterpret_cast<u16*>(Hraw + wave * 4096);  // [16 rows][128 cols] bf16, XOR-swizzled

    const float s_in = *ps_in, s1i = *ps1i, s1o = *ps1o;
    const float s2i = *ps2i, s2o = *ps2o, s3i = *ps3i, s3o = *ps3o;
    const float inv_sin = 1.f / s_in, inv_s1i = 1.f / s1i, inv_s1o = 1.f / s1o;
    const float inv_s2i = 1.f / s2i, inv_s2o = 1.f / s2o;
    const float inv_s3i = 1.f / s3i, inv_s3o = 1.f / s3o;
    const float alpha1 = alphas[0], alpha2 = alphas[1], alpha3 = alphas[2];

    // A-frag ownership: row = lane&15 (within wave's 16-row tile), kgroup = lane>>4
    const int rA = lane & 15;
    const int gA = lane >> 4;
    const size_t arow = (size_t)(row0 + wave * 16 + rA) * 784;
    const float* __restrict__ inA = input + arow + gA * 8;
    float* __restrict__ h0A = h0 + arow + gA * 8;
    const u16* bw1 = Wb1 + (size_t)lane * 8;

    f32x4 acc1[8];
#pragma unroll
    for (int n = 0; n < 8; ++n) acc1[n] = f32x4{0.f, 0.f, 0.f, 0.f};

    // quant + h0-store + pack + 8 MFMAs for one kstep's 8 owned elements
    auto consume = [&](int ksq, f32x4 va, f32x4 vb, bool dostore) {
        float q[8];
#pragma unroll
        for (int j = 0; j < 4; ++j) {
            q[j]     = quantq_inv(va[j], inv_sin);
            q[4 + j] = quantq_inv(vb[j], inv_sin);
        }
        if (dostore) {
            f32x4 ha = {q[0] * s_in, q[1] * s_in, q[2] * s_in, q[3] * s_in};
            f32x4 hb = {q[4] * s_in, q[5] * s_in, q[6] * s_in, q[7] * s_in};
            float* hp = h0A + ksq * 32;
            __builtin_nontemporal_store(ha, reinterpret_cast<f32x4*>(hp));
            __builtin_nontemporal_store(hb, reinterpret_cast<f32x4*>(hp + 4));
        }
        u16x8 qb;
#pragma unroll
        for (int j = 0; j < 8; ++j) qb[j] = (u16)(__float_as_uint(q[j]) >> 16);
        union { u16x8 u; bf16x8 b; } cvt;
        cvt.u = qb;
        const bf16x8 a = cvt.b;
        const u16* bp = bw1 + (size_t)ksq * 4096;
#pragma unroll
        for (int n = 0; n < 8; ++n) {
            const bf16x8 b = *reinterpret_cast<const bf16x8*>(bp + n * 512);
            acc1[n] = __builtin_amdgcn_mfma_f32_16x16x32_bf16(a, b, acc1[n], 0, 0, 0);
        }
    };

    // ---- layer 1: K=784 padded to 800 (25 ksteps), 4-deep static ring ------
    f32x4 s0a, s0b, s1a, s1b, s2a, s2b, s3a, s3b;
    s0a = *reinterpret_cast<const f32x4*>(inA + 0 * 32);
    s0b = *reinterpret_cast<const f32x4*>(inA + 0 * 32 + 4);
    s1a = *reinterpret_cast<const f32x4*>(inA + 1 * 32);
    s1b = *reinterpret_cast<const f32x4*>(inA + 1 * 32 + 4);
    s2a = *reinterpret_cast<const f32x4*>(inA + 2 * 32);
    s2b = *reinterpret_cast<const f32x4*>(inA + 2 * 32 + 4);
    s3a = *reinterpret_cast<const f32x4*>(inA + 3 * 32);
    s3b = *reinterpret_cast<const f32x4*>(inA + 3 * 32 + 4);

#define L1_STEP(K, SA, SB)                                                    \
    {                                                                         \
        f32x4 na, nb;                                                         \
        const int t_ = (K) + 4;                                               \
        if (t_ < 24) {                                                        \
            na = *reinterpret_cast<const f32x4*>(inA + t_ * 32);              \
            nb = *reinterpret_cast<const f32x4*>(inA + t_ * 32 + 4);          \
        } else if (t_ == 24) {                                                \
            if (gA < 2) {                                                     \
                na = *reinterpret_cast<const f32x4*>(inA + 768);              \
                nb = *reinterpret_cast<const f32x4*>(inA + 768 + 4);          \
            } else {                                                          \
                na = f32x4{0.f, 0.f, 0.f, 0.f};                               \
                nb = f32x4{0.f, 0.f, 0.f, 0.f};                               \
            }                                                                 \
        } else {                                                              \
            na = SA; nb = SB;                                                 \
        }                                                                     \
        consume((K), SA, SB, true);                                           \
        SA = na; SB = nb;                                                     \
    }

#pragma unroll
    for (int base = 0; base < 24; base += 4) {
        L1_STEP(base + 0, s0a, s0b);
        L1_STEP(base + 1, s1a, s1b);
        L1_STEP(base + 2, s2a, s2b);
        L1_STEP(base + 3, s3a, s3b);
    }
#undef L1_STEP

    // tail kstep ksq=24 (cols 768..800; valid only for gA<2, zeros otherwise)
    {
        float q[8];
#pragma unroll
        for (int j = 0; j < 4; ++j) {
            q[j]     = quantq_inv(s0a[j], inv_sin);
            q[4 + j] = quantq_inv(s0b[j], inv_sin);
        }
        if (gA < 2) {
            f32x4 ha = {q[0] * s_in, q[1] * s_in, q[2] * s_in, q[3] * s_in};
            f32x4 hb = {q[4] * s_in, q[5] * s_in, q[6] * s_in, q[7] * s_in};
            float* hp = h0A + 24 * 32;
            __builtin_nontemporal_store(ha, reinterpret_cast<f32x4*>(hp));
            __builtin_nontemporal_store(hb, reinterpret_cast<f32x4*>(hp + 4));
        }
        u16x8 qb;
#pragma unroll
        for (int j = 0; j < 8; ++j) qb[j] = (u16)(__float_as_uint(q[j]) >> 16);
        union { u16x8 u; bf16x8 b; } cvt;
        cvt.u = qb;
        const bf16x8 a = cvt.b;
        const u16* bp = bw1 + (size_t)24 * 4096;
#pragma unroll
        for (int n = 0; n < 8; ++n) {
            const bf16x8 b = *reinterpret_cast<const bf16x8*>(bp + n * 512);
            acc1[n] = __builtin_amdgcn_mfma_f32_16x16x32_bf16(a, b, acc1[n], 0, 0, 0);
        }
    }

    const int cl = lane & 15;
    const int rh = lane >> 4;

    // coalesced NT row-store of a staged 16x128 bf16 tile, scaled by s
    auto flush_H = [&](float* __restrict__ dst, float s) {
#pragma unroll
        for (int it = 0; it < 8; ++it) {
            const int row = it * 2 + (lane >> 5);
            const int seg = (lane & 31) * 4;
            const int idx = (row * 128 + seg) ^ ((row & 7) << 3);
            const u16x4 v = *reinterpret_cast<const u16x4*>(&Hb[idx]);
            f32x4 f = {bfbits_to_f32(v[0]) * s, bfbits_to_f32(v[1]) * s,
                       bfbits_to_f32(v[2]) * s, bfbits_to_f32(v[3]) * s};
            __builtin_nontemporal_store(f, reinterpret_cast<f32x4*>(
                dst + (size_t)(row0 + wave * 16 + row) * 128 + seg));
        }
    };

    // ---- layer 1 epilogue: requantize, stage A2 + H, flush h1 coalesced ----
    {
        const float a1s = alpha1 * s_in;
#pragma unroll
        for (int n = 0; n < 8; ++n) {
            const int col = n * 16 + cl;
            const float bias = bias1[col];
            const int ks = n >> 1;
            const int gk = ((n & 1) * 2) + (cl >> 3);
            const int jd = cl & 7;
#pragma unroll
            for (int j = 0; j < 4; ++j) {
                const int rl = rh * 4 + j;
                float x = a1s * acc1[n][j] + bias;
                x = quantq_inv(x, inv_s1i) * s1i;
                x = fmaxf(x, 0.f);
                const float qv = quantq_inv(x, inv_s1o);
                const u16 qb = (u16)(__float_as_uint(qv) >> 16);
                A2[(((ks * 4 + wave) * 64) + (gk * 16 + rl)) * 8 + jd] = qb;
                Hb[(rl * 128 + col) ^ ((rl & 7) << 3)] = qb;
            }
        }
        flush_H(h1, s1o);
    }

    // ---- layer 2: K=128 (4 ksteps), B-frags straight from global (L1) ----
    f32x4 acc2[8];
#pragma unroll
    for (int n = 0; n < 8; ++n) acc2[n] = f32x4{0.f, 0.f, 0.f, 0.f};
#pragma unroll
    for (int ks = 0; ks < 4; ++ks) {
        const bf16x8 a = *reinterpret_cast<const bf16x8*>(&A2[((ks * 4 + wave) * 64 + lane) * 8]);
#pragma unroll
        for (int n = 0; n < 8; ++n) {
            const bf16x8 b = *reinterpret_cast<const bf16x8*>(Wb2 + ((size_t)(ks * 8 + n) * 64 + lane) * 8);
            acc2[n] = __builtin_amdgcn_mfma_f32_16x16x32_bf16(a, b, acc2[n], 0, 0, 0);
        }
    }

    // ---- layer 2 epilogue ----
    {
        const float a2s = alpha2 * s1o;
#pragma unroll
        for (int n = 0; n < 8; ++n) {
            const int col = n * 16 + cl;
            const float bias = bias2[col];
            const int ks = n >> 1;
            const int gk = ((n & 1) * 2) + (cl >> 3);
            const int jd = cl & 7;
#pragma unroll
            for (int j = 0; j < 4; ++j) {
                const int rl = rh * 4 + j;
                float x = a2s * acc2[n][j] + bias;
                x = quantq_inv(x, inv_s2i) * s2i;
                x = fmaxf(x, 0.f);
                const float qv = quantq_inv(x, inv_s2o);
                const u16 qb = (u16)(__float_as_uint(qv) >> 16);
                A2[(((ks * 4 + wave) * 64) + (gk * 16 + rl)) * 8 + jd] = qb;
                Hb[(rl * 128 + col) ^ ((rl & 7) << 3)] = qb;
            }
        }
        flush_H(h2, s2o);
    }

    // ---- layer 3: K=128, single ntile (N=10 padded to 16) ----
    f32x4 acc3 = f32x4{0.f, 0.f, 0.f, 0.f};
#pragma unroll
    for (int ks = 0; ks < 4; ++ks) {
        const bf16x8 a = *reinterpret_cast<const bf16x8*>(&A2[((ks * 4 + wave) * 64 + lane) * 8]);
        const bf16x8 b = *reinterpret_cast<const bf16x8*>(Wb3 + ((size_t)ks * 64 + lane) * 8);
        acc3 = __builtin_amdgcn_mfma_f32_16x16x32_bf16(a, b, acc3, 0, 0, 0);
    }

    // ---- layer 3 epilogue: sigmoid + quant, staged -> 640B contiguous NT ---
    {
        float* Hf = reinterpret_cast<float*>(Hraw + wave * 4096);  // [16][10] f32
        if (cl < 10) {
            const float a3s = alpha3 * s2o;
            const float bias = bias3[cl];
#pragma unroll
            for (int j = 0; j < 4; ++j) {
                const int rl = rh * 4 + j;
                float x = a3s * acc3[j] + bias;
                x = quantq_inv(x, inv_s3i) * s3i;
                const float sg = 1.f / (1.f + expf(-x));
                Hf[rl * 10 + cl] = quantq_inv(sg, inv_s3o) * s3o;
            }
        }
        if (lane < 40) {
            const f32x4 v = *reinterpret_cast<const f32x4*>(&Hf[lane * 4]);
            const size_t dst = (size_t)(row0 + wave * 16) * 10 + lane * 4;
            __builtin_nontemporal_store(v, reinterpret_cast<f32x4*>(out0 + dst));
            __builtin_nontemporal_store(v, reinterpret_cast<f32x4*>(h3 + dst));
        }
    }
}

extern "C" void kernel_launch(void* const* d_in, const int* in_sizes, int n_in,
                              void* d_out, int out_size, void* d_ws, size_t ws_size,
                              hipStream_t stream) {
    const float* input = (const float*)d_in[0];
    const float* w1    = (const float*)d_in[1];
    const float* bias1 = (const float*)d_in[2];
    const float* w2    = (const float*)d_in[3];
    const float* bias2 = (const float*)d_in[4];
    const float* w3    = (const float*)d_in[5];
    const float* bias3 = (const float*)d_in[6];
    const float* s_in  = (const float*)d_in[7];
    const float* s1i   = (const float*)d_in[8];
    const float* s1o   = (const float*)d_in[9];
    const float* s2i   = (const float*)d_in[10];
    const float* s2o   = (const float*)d_in[11];
    const float* s3i   = (const float*)d_in[12];
    const float* s3o   = (const float*)d_in[13];

    float* out = (float*)d_out;
    // output order: (x_final, h0, h1, h2, h3)
    float* out0 = out;
    float* h0 = out + 655360;                   // 65536*10
    float* h1 = out + 52035584;                 // + 65536*784
    float* h2 = out + 60424192;                 // + 65536*128
    float* h3 = out + 68812800;                 // + 65536*128

    float* alphas  = (float*)d_ws;                        // 3 floats
    float* partial = (float*)((char*)d_ws + 16);          // 96 floats
    u16*   Wb1     = (u16*)((char*)d_ws + 512);           // 120832 u16

    alpha_part<<<96, 256, 0, stream>>>(w1, w2, w3, partial);
    pack_kernel<<<472, 256, 0, stream>>>(w1, w2, w3, Wb1, partial, alphas);
    fused_kernel<<<1024, 256, 0, stream>>>(input, bias1, bias2, bias3,
                                           s_in, s1i, s1o, s2i, s2o, s3i, s3o,
                                           alphas, Wb1,
                                           out0, h0, h1, h2, h3);
}

// Round 9
// 106.423 us; speedup vs baseline: 1.7753x; 1.0227x over previous
//
#include <hip/hip_runtime.h>
#include <math.h>

typedef __bf16 bf16x8 __attribute__((ext_vector_type(8)));
typedef float f32x4 __attribute__((ext_vector_type(4)));
typedef unsigned short u16;
typedef u16 u16x8 __attribute__((ext_vector_type(8)));
typedef u16 u16x4 __attribute__((ext_vector_type(4)));

// clip(round(x*inv), -128, 127) -- rintf = round-half-even, matches jnp.round
__device__ __forceinline__ float quantq_inv(float x, float inv) {
    return fminf(fmaxf(rintf(x * inv), -128.f), 127.f);
}

__device__ __forceinline__ u16 sign_bf16(float w) {
    return (w > 0.f) ? (u16)0x3F80 : ((w < 0.f) ? (u16)0xBF80 : (u16)0);
}

__device__ __forceinline__ float bfbits_to_f32(u16 b) {
    return __uint_as_float(((unsigned)b) << 16);
}

// ---------------- single prep kernel: pack sign(w) + |w| partial sums -------
// blocks 0..471: pack sign(w) frag-ready (bf16 +-1).
//   dest layout per kstep(K=32): [ntile][lane][8]; B-operand of
//   mfma_f32_16x16x32_bf16: lane = (kk/8)*16 + (col%16), j = kk%8
//   Wb1: K 784->800 (25 ksteps, 8 ntiles) = 102400 u16
//   Wb2: K=128 (4 ksteps, 8 ntiles)       =  16384 u16
//   Wb3: K=128 (4 ksteps, 1 ntile, N 10->16) = 2048 u16
// blocks 472..567: deterministic per-slice |w| partial sums (3 x 32 slices).
__global__ void prep_kernel(const float* __restrict__ w1,
                            const float* __restrict__ w2,
                            const float* __restrict__ w3,
                            u16* __restrict__ Wb1,
                            float* __restrict__ partial) {
    const int bid = blockIdx.x;
    if (bid < 472) {
        u16* Wb2 = Wb1 + 102400;
        u16* Wb3 = Wb2 + 16384;
        int idx = bid * 256 + threadIdx.x;
        if (idx < 102400) {
            int k = idx >> 7, n = idx & 127;
            u16 v = (k < 784) ? sign_bf16(w1[k * 128 + n]) : (u16)0;
            int dest = ((((k >> 5) * 8 + (n >> 4)) * 64) + ((((k & 31) >> 3) << 4) | (n & 15))) * 8 + (k & 7);
            Wb1[dest] = v;
        } else if (idx < 102400 + 16384) {
            int i = idx - 102400;
            int k = i >> 7, n = i & 127;
            u16 v = sign_bf16(w2[k * 128 + n]);
            int dest = ((((k >> 5) * 8 + (n >> 4)) * 64) + ((((k & 31) >> 3) << 4) | (n & 15))) * 8 + (k & 7);
            Wb2[dest] = v;
        } else if (idx < 102400 + 16384 + 2048) {
            int i = idx - 102400 - 16384;
            int k = i >> 4, n = i & 15;
            u16 v = (n < 10) ? sign_bf16(w3[k * 10 + n]) : (u16)0;
            int dest = (((k >> 5) * 64) + ((((k & 31) >> 3) << 4) | n)) * 8 + (k & 7);
            Wb3[dest] = v;
        }
    } else {
        __shared__ float red[256];
        const int abid = bid - 472;
        const int m = abid >> 5, i = abid & 31;
        const float* w = (m == 0) ? w1 : ((m == 1) ? w2 : w3);
        const int n = (m == 0) ? 100352 : ((m == 1) ? 16384 : 1280);
        const int chunk = n >> 5;  // all divisible by 32
        const float* p = w + i * chunk;
        float s = 0.f;
        for (int t = threadIdx.x; t < chunk; t += 256) s += fabsf(p[t]);
        red[threadIdx.x] = s;
        __syncthreads();
        for (int off = 128; off > 0; off >>= 1) {
            if ((int)threadIdx.x < off) red[threadIdx.x] += red[threadIdx.x + off];
            __syncthreads();
        }
        if (threadIdx.x == 0) partial[abid] = red[0];
    }
}

// ---------------- fused forward: 64 rows/block, 4 waves, ZERO barriers ------
// R8 structure (best: 108.8us): NT stores everywhere, epilogue stores staged
// through LDS and flushed as full-line contiguous NT bursts. This round:
// alpha finalize moved in here (96 uniform scalar loads, deterministic,
// identical across blocks) so prep collapses to one launch.
__global__ __launch_bounds__(256, 4) void fused_kernel(
    const float* __restrict__ input,
    const float* __restrict__ bias1, const float* __restrict__ bias2,
    const float* __restrict__ bias3,
    const float* __restrict__ ps_in, const float* __restrict__ ps1i,
    const float* __restrict__ ps1o, const float* __restrict__ ps2i,
    const float* __restrict__ ps2o, const float* __restrict__ ps3i,
    const float* __restrict__ ps3o,
    const float* __restrict__ partial, const u16* __restrict__ Wb1,
    float* __restrict__ out0, float* __restrict__ h0, float* __restrict__ h1,
    float* __restrict__ h2, float* __restrict__ h3)
{
    const u16* Wb2 = Wb1 + 102400;
    const u16* Wb3 = Wb2 + 16384;

    // wave-local inter-layer exchange only (no block barriers anywhere)
    __shared__ u16 A2[8192];       // 16KB frag-layout activations
    __shared__ char Hraw[16384];   // 16KB: per-wave 4KB store-staging buffer

    const int tid = threadIdx.x;
    const int wave = tid >> 6, lane = tid & 63;
    const int row0 = blockIdx.x * 64;

    u16* Hb = reinterpret_cast<u16*>(Hraw + wave * 4096);  // [16 rows][128 cols] bf16, XOR-swizzled

    const float s_in = *ps_in, s1i = *ps1i, s1o = *ps1o;
    const float s2i = *ps2i, s2o = *ps2o, s3i = *ps3i, s3o = *ps3o;
    const float inv_sin = 1.f / s_in, inv_s1i = 1.f / s1i, inv_s1o = 1.f / s1o;
    const float inv_s2i = 1.f / s2i, inv_s2o = 1.f / s2o;
    const float inv_s3i = 1.f / s3i, inv_s3o = 1.f / s3o;

    // A-frag ownership: row = lane&15 (within wave's 16-row tile), kgroup = lane>>4
    const int rA = lane & 15;
    const int gA = lane >> 4;
    const size_t arow = (size_t)(row0 + wave * 16 + rA) * 784;
    const float* __restrict__ inA = input + arow + gA * 8;
    float* __restrict__ h0A = h0 + arow + gA * 8;
    const u16* bw1 = Wb1 + (size_t)lane * 8;

    f32x4 acc1[8];
#pragma unroll
    for (int n = 0; n < 8; ++n) acc1[n] = f32x4{0.f, 0.f, 0.f, 0.f};

    // quant + h0-store + pack + 8 MFMAs for one kstep's 8 owned elements
    auto consume = [&](int ksq, f32x4 va, f32x4 vb, bool dostore) {
        float q[8];
#pragma unroll
        for (int j = 0; j < 4; ++j) {
            q[j]     = quantq_inv(va[j], inv_sin);
            q[4 + j] = quantq_inv(vb[j], inv_sin);
        }
        if (dostore) {
            f32x4 ha = {q[0] * s_in, q[1] * s_in, q[2] * s_in, q[3] * s_in};
            f32x4 hb = {q[4] * s_in, q[5] * s_in, q[6] * s_in, q[7] * s_in};
            float* hp = h0A + ksq * 32;
            __builtin_nontemporal_store(ha, reinterpret_cast<f32x4*>(hp));
            __builtin_nontemporal_store(hb, reinterpret_cast<f32x4*>(hp + 4));
        }
        u16x8 qb;
#pragma unroll
        for (int j = 0; j < 8; ++j) qb[j] = (u16)(__float_as_uint(q[j]) >> 16);
        union { u16x8 u; bf16x8 b; } cvt;
        cvt.u = qb;
        const bf16x8 a = cvt.b;
        const u16* bp = bw1 + (size_t)ksq * 4096;
#pragma unroll
        for (int n = 0; n < 8; ++n) {
            const bf16x8 b = *reinterpret_cast<const bf16x8*>(bp + n * 512);
            acc1[n] = __builtin_amdgcn_mfma_f32_16x16x32_bf16(a, b, acc1[n], 0, 0, 0);
        }
    };

    // ---- layer 1: K=784 padded to 800 (25 ksteps), 4-deep static ring ------
    f32x4 s0a, s0b, s1a, s1b, s2a, s2b, s3a, s3b;
    s0a = *reinterpret_cast<const f32x4*>(inA + 0 * 32);
    s0b = *reinterpret_cast<const f32x4*>(inA + 0 * 32 + 4);
    s1a = *reinterpret_cast<const f32x4*>(inA + 1 * 32);
    s1b = *reinterpret_cast<const f32x4*>(inA + 1 * 32 + 4);
    s2a = *reinterpret_cast<const f32x4*>(inA + 2 * 32);
    s2b = *reinterpret_cast<const f32x4*>(inA + 2 * 32 + 4);
    s3a = *reinterpret_cast<const f32x4*>(inA + 3 * 32);
    s3b = *reinterpret_cast<const f32x4*>(inA + 3 * 32 + 4);

#define L1_STEP(K, SA, SB)                                                    \
    {                                                                         \
        f32x4 na, nb;                                                         \
        const int t_ = (K) + 4;                                               \
        if (t_ < 24) {                                                        \
            na = *reinterpret_cast<const f32x4*>(inA + t_ * 32);              \
            nb = *reinterpret_cast<const f32x4*>(inA + t_ * 32 + 4);          \
        } else if (t_ == 24) {                                                \
            if (gA < 2) {                                                     \
                na = *reinterpret_cast<const f32x4*>(inA + 768);              \
                nb = *reinterpret_cast<const f32x4*>(inA + 768 + 4);          \
            } else {                                                          \
                na = f32x4{0.f, 0.f, 0.f, 0.f};                               \
                nb = f32x4{0.f, 0.f, 0.f, 0.f};                               \
            }                                                                 \
        } else {                                                              \
            na = SA; nb = SB;                                                 \
        }                                                                     \
        consume((K), SA, SB, true);                                           \
        SA = na; SB = nb;                                                     \
    }

#pragma unroll
    for (int base = 0; base < 24; base += 4) {
        L1_STEP(base + 0, s0a, s0b);
        L1_STEP(base + 1, s1a, s1b);
        L1_STEP(base + 2, s2a, s2b);
        L1_STEP(base + 3, s3a, s3b);
    }
#undef L1_STEP

    // tail kstep ksq=24 (cols 768..800; valid only for gA<2, zeros otherwise)
    {
        float q[8];
#pragma unroll
        for (int j = 0; j < 4; ++j) {
            q[j]     = quantq_inv(s0a[j], inv_sin);
            q[4 + j] = quantq_inv(s0b[j], inv_sin);
        }
        if (gA < 2) {
            f32x4 ha = {q[0] * s_in, q[1] * s_in, q[2] * s_in, q[3] * s_in};
            f32x4 hb = {q[4] * s_in, q[5] * s_in, q[6] * s_in, q[7] * s_in};
            float* hp = h0A + 24 * 32;
            __builtin_nontemporal_store(ha, reinterpret_cast<f32x4*>(hp));
            __builtin_nontemporal_store(hb, reinterpret_cast<f32x4*>(hp + 4));
        }
        u16x8 qb;
#pragma unroll
        for (int j = 0; j < 8; ++j) qb[j] = (u16)(__float_as_uint(q[j]) >> 16);
        union { u16x8 u; bf16x8 b; } cvt;
        cvt.u = qb;
        const bf16x8 a = cvt.b;
        const u16* bp = bw1 + (size_t)24 * 4096;
#pragma unroll
        for (int n = 0; n < 8; ++n) {
            const bf16x8 b = *reinterpret_cast<const bf16x8*>(bp + n * 512);
            acc1[n] = __builtin_amdgcn_mfma_f32_16x16x32_bf16(a, b, acc1[n], 0, 0, 0);
        }
    }

    // ---- alpha finalize (uniform scalar work, deterministic per block) ----
    float alpha1, alpha2, alpha3;
    {
        float sa = 0.f, sb = 0.f, sc = 0.f;
#pragma unroll
        for (int i = 0; i < 32; ++i) {
            sa += partial[i];
            sb += partial[32 + i];
            sc += partial[64 + i];
        }
        alpha1 = sa / 100352.f;
        alpha2 = sb / 16384.f;
        alpha3 = sc / 1280.f;
    }

    const int cl = lane & 15;
    const int rh = lane >> 4;

    // coalesced NT row-store of a staged 16x128 bf16 tile, scaled by s
    auto flush_H = [&](float* __restrict__ dst, float s) {
#pragma unroll
        for (int it = 0; it < 8; ++it) {
            const int row = it * 2 + (lane >> 5);
            const int seg = (lane & 31) * 4;
            const int idx = (row * 128 + seg) ^ ((row & 7) << 3);
            const u16x4 v = *reinterpret_cast<const u16x4*>(&Hb[idx]);
            f32x4 f = {bfbits_to_f32(v[0]) * s, bfbits_to_f32(v[1]) * s,
                       bfbits_to_f32(v[2]) * s, bfbits_to_f32(v[3]) * s};
            __builtin_nontemporal_store(f, reinterpret_cast<f32x4*>(
                dst + (size_t)(row0 + wave * 16 + row) * 128 + seg));
        }
    };

    // ---- layer 1 epilogue: requantize, stage A2 + H, flush h1 coalesced ----
    {
        const float a1s = alpha1 * s_in;
#pragma unroll
        for (int n = 0; n < 8; ++n) {
            const int col = n * 16 + cl;
            const float bias = bias1[col];
            const int ks = n >> 1;
            const int gk = ((n & 1) * 2) + (cl >> 3);
            const int jd = cl & 7;
#pragma unroll
            for (int j = 0; j < 4; ++j) {
                const int rl = rh * 4 + j;
                float x = a1s * acc1[n][j] + bias;
                x = quantq_inv(x, inv_s1i) * s1i;
                x = fmaxf(x, 0.f);
                const float qv = quantq_inv(x, inv_s1o);
                const u16 qb = (u16)(__float_as_uint(qv) >> 16);
                A2[(((ks * 4 + wave) * 64) + (gk * 16 + rl)) * 8 + jd] = qb;
                Hb[(rl * 128 + col) ^ ((rl & 7) << 3)] = qb;
            }
        }
        flush_H(h1, s1o);
    }

    // ---- layer 2: K=128 (4 ksteps), B-frags straight from global (L1) ----
    f32x4 acc2[8];
#pragma unroll
    for (int n = 0; n < 8; ++n) acc2[n] = f32x4{0.f, 0.f, 0.f, 0.f};
#pragma unroll
    for (int ks = 0; ks < 4; ++ks) {
        const bf16x8 a = *reinterpret_cast<const bf16x8*>(&A2[((ks * 4 + wave) * 64 + lane) * 8]);
#pragma unroll
        for (int n = 0; n < 8; ++n) {
            const bf16x8 b = *reinterpret_cast<const bf16x8*>(Wb2 + ((size_t)(ks * 8 + n) * 64 + lane) * 8);
            acc2[n] = __builtin_amdgcn_mfma_f32_16x16x32_bf16(a, b, acc2[n], 0, 0, 0);
        }
    }

    // ---- layer 2 epilogue ----
    {
        const float a2s = alpha2 * s1o;
#pragma unroll
        for (int n = 0; n < 8; ++n) {
            const int col = n * 16 + cl;
            const float bias = bias2[col];
            const int ks = n >> 1;
            const int gk = ((n & 1) * 2) + (cl >> 3);
            const int jd = cl & 7;
#pragma unroll
            for (int j = 0; j < 4; ++j) {
                const int rl = rh * 4 + j;
                float x = a2s * acc2[n][j] + bias;
                x = quantq_inv(x, inv_s2i) * s2i;
                x = fmaxf(x, 0.f);
                const float qv = quantq_inv(x, inv_s2o);
                const u16 qb = (u16)(__float_as_uint(qv) >> 16);
                A2[(((ks * 4 + wave) * 64) + (gk * 16 + rl)) * 8 + jd] = qb;
                Hb[(rl * 128 + col) ^ ((rl & 7) << 3)] = qb;
            }
        }
        flush_H(h2, s2o);
    }

    // ---- layer 3: K=128, single ntile (N=10 padded to 16) ----
    f32x4 acc3 = f32x4{0.f, 0.f, 0.f, 0.f};
#pragma unroll
    for (int ks = 0; ks < 4; ++ks) {
        const bf16x8 a = *reinterpret_cast<const bf16x8*>(&A2[((ks * 4 + wave) * 64 + lane) * 8]);
        const bf16x8 b = *reinterpret_cast<const bf16x8*>(Wb3 + ((size_t)ks * 64 + lane) * 8);
        acc3 = __builtin_amdgcn_mfma_f32_16x16x32_bf16(a, b, acc3, 0, 0, 0);
    }

    // ---- layer 3 epilogue: sigmoid + quant, staged -> 640B contiguous NT ---
    {
        float* Hf = reinterpret_cast<float*>(Hraw + wave * 4096);  // [16][10] f32
        if (cl < 10) {
            const float a3s = alpha3 * s2o;
            const float bias = bias3[cl];
#pragma unroll
            for (int j = 0; j < 4; ++j) {
                const int rl = rh * 4 + j;
                float x = a3s * acc3[j] + bias;
                x = quantq_inv(x, inv_s3i) * s3i;
                const float sg = 1.f / (1.f + expf(-x));
                Hf[rl * 10 + cl] = quantq_inv(sg, inv_s3o) * s3o;
            }
        }
        if (lane < 40) {
            const f32x4 v = *reinterpret_cast<const f32x4*>(&Hf[lane * 4]);
            const size_t dst = (size_t)(row0 + wave * 16) * 10 + lane * 4;
            __builtin_nontemporal_store(v, reinterpret_cast<f32x4*>(out0 + dst));
            __builtin_nontemporal_store(v, reinterpret_cast<f32x4*>(h3 + dst));
        }
    }
}

extern "C" void kernel_launch(void* const* d_in, const int* in_sizes, int n_in,
                              void* d_out, int out_size, void* d_ws, size_t ws_size,
                              hipStream_t stream) {
    const float* input = (const float*)d_in[0];
    const float* w1    = (const float*)d_in[1];
    const float* bias1 = (const float*)d_in[2];
    const float* w2    = (const float*)d_in[3];
    const float* bias2 = (const float*)d_in[4];
    const float* w3    = (const float*)d_in[5];
    const float* bias3 = (const float*)d_in[6];
    const float* s_in  = (const float*)d_in[7];
    const float* s1i   = (const float*)d_in[8];
    const float* s1o   = (const float*)d_in[9];
    const float* s2i   = (const float*)d_in[10];
    const float* s2o   = (const float*)d_in[11];
    const float* s3i   = (const float*)d_in[12];
    const float* s3o   = (const float*)d_in[13];

    float* out = (float*)d_out;
    // output order: (x_final, h0, h1, h2, h3)
    float* out0 = out;
    float* h0 = out + 655360;                   // 65536*10
    float* h1 = out + 52035584;                 // + 65536*784
    float* h2 = out + 60424192;                 // + 65536*128
    float* h3 = out + 68812800;                 // + 65536*128

    float* partial = (float*)d_ws;                        // 96 floats
    u16*   Wb1     = (u16*)((char*)d_ws + 512);           // 120832 u16

    prep_kernel<<<568, 256, 0, stream>>>(w1, w2, w3, Wb1, partial);
    fused_kernel<<<1024, 256, 0, stream>>>(input, bias1, bias2, bias3,
                                           s_in, s1i, s1o, s2i, s2o, s3i, s3o,
                                           partial, Wb1,
                                           out0, h0, h1, h2, h3);
}